// Round 1
// baseline (1107.629 us; speedup 1.0000x reference)
//
#include <hip/hip_runtime.h>
#include <stdint.h>

typedef __attribute__((ext_vector_type(8))) short short8;
typedef __attribute__((ext_vector_type(4))) float floatx4;

#define GLOAD_LDS16(gp, lp)                                        \
  __builtin_amdgcn_global_load_lds(                                \
      (const __attribute__((address_space(1))) void*)(gp),         \
      (__attribute__((address_space(3))) void*)(lp), 16, 0, 0)

__device__ __forceinline__ float bf2f(unsigned short u) {
  union { unsigned int i; float f; } x;
  x.i = ((unsigned int)u) << 16;
  return x.f;
}
__device__ __forceinline__ unsigned short f2bf(float f) {
  union { float f; unsigned int i; } x;
  x.f = f;
  unsigned int r = x.i + 0x7FFFu + ((x.i >> 16) & 1u);
  return (unsigned short)(r >> 16);
}

// ---------------------------------------------------------------------------
// Generic A*B^T GEMM, bf16 inputs, f32 accumulate.
//   A  : [M][K] row-major bf16 (+ z*strideA)
//   Bt : [N][K] row-major bf16 (+ z*strideB)
//   out[z*strideOut + row*N + col]
// EPI 0: f32 out = acc + bias[row]
// EPI 1: bf16 out = acc + bias[row]
// EPI 2: f32 out = acc + addSrc[idx]   (addSrc may alias outP; disjoint idx)
// Tile: BM=BN=128, BK=64, 256 threads (4 waves, each 64x64 out).
// LDS XOR-swizzle (chunk ^= row&7) applied via pre-swizzled GLOBAL source
// addresses (global_load_lds dest must stay linear), un-swizzled on ds_read.
// ---------------------------------------------------------------------------
template <int EPI>
__launch_bounds__(256, 2)
__global__ void gemm_abt(const unsigned short* __restrict__ A, long strideA,
                         const unsigned short* __restrict__ Bt, long strideB,
                         const float* __restrict__ bias,
                         const float* addSrc, void* outP,
                         long strideOut, int N, int K)
{
  __shared__ short Asm[128 * 64];
  __shared__ short Bsm[128 * 64];

  const int tid  = threadIdx.x;
  const int wave = tid >> 6;
  const int lane = tid & 63;
  const int z  = blockIdx.z;
  const int m0 = blockIdx.y * 128;
  const int n0 = blockIdx.x * 128;

  const unsigned short* Ab = A  + (size_t)z * strideA;
  const unsigned short* Bb = Bt + (size_t)z * strideB;

  // Staging: wave w stages rows [w*32, w*32+32) of each tile, 4 insts x 8 rows.
  // lane -> local row (lane>>3), 16B chunk (lane&7); data chunk = (lane&7)^(row&7).
  const int lr  = lane >> 3;
  const int swz = (lane & 7) ^ lr;
  const unsigned short* gA = Ab + (size_t)(m0 + wave * 32 + lr) * K + swz * 8;
  const unsigned short* gB = Bb + (size_t)(n0 + wave * 32 + lr) * K + swz * 8;
  short* lA = Asm + wave * 32 * 64;
  short* lB = Bsm + wave * 32 * 64;

  floatx4 acc[4][4];
#pragma unroll
  for (int i = 0; i < 4; ++i)
#pragma unroll
    for (int j = 0; j < 4; ++j)
#pragma unroll
      for (int q = 0; q < 4; ++q) acc[i][j][q] = 0.f;

  const int g    = lane >> 4;       // k-group 0..3
  const int ln16 = lane & 15;       // frag row/col
  const int wr   = (wave >> 1) * 64;
  const int wc   = (wave & 1) * 64;
  const int xm   = (lane & 7) * 8;  // xor mask in elements (row&7 == lane&7 for frag rows)
  const int ck0  = (g * 8) ^ xm;    // k-step 0 column offset (swizzled)
  const int ck1  = (32 + g * 8) ^ xm;

  const int nkt = K >> 6;
  for (int kt = 0; kt < nkt; ++kt) {
#pragma unroll
    for (int i = 0; i < 4; ++i) {
      GLOAD_LDS16(gA + (size_t)i * 8 * K, lA + i * 512);
      GLOAD_LDS16(gB + (size_t)i * 8 * K, lB + i * 512);
    }
    __syncthreads();   // compiler emits vmcnt(0) drain before barrier
#pragma unroll
    for (int kk = 0; kk < 2; ++kk) {
      const int ck = kk ? ck1 : ck0;
      short8 a[4], b[4];
#pragma unroll
      for (int m = 0; m < 4; ++m)
        a[m] = *(const short8*)(Asm + (wr + m * 16 + ln16) * 64 + ck);
#pragma unroll
      for (int n = 0; n < 4; ++n)
        b[n] = *(const short8*)(Bsm + (wc + n * 16 + ln16) * 64 + ck);
#pragma unroll
      for (int m = 0; m < 4; ++m)
#pragma unroll
        for (int n = 0; n < 4; ++n)
          acc[m][n] = __builtin_amdgcn_mfma_f32_16x16x32_bf16(a[m], b[n], acc[m][n], 0, 0, 0);
    }
    __syncthreads();
    gA += 64;
    gB += 64;
  }

  // Epilogue. C/D frag: col = lane&15, row = (lane>>4)*4 + q  [m89-verified]
#pragma unroll
  for (int m = 0; m < 4; ++m) {
#pragma unroll
    for (int q = 0; q < 4; ++q) {
      const int row = m0 + wr + m * 16 + g * 4 + q;
      float bv = 0.f;
      if constexpr (EPI != 2) bv = bias[row];
#pragma unroll
      for (int n = 0; n < 4; ++n) {
        const int col = n0 + wc + n * 16 + ln16;
        const size_t idx = (size_t)z * strideOut + (size_t)row * N + col;
        const float v = acc[m][n][q] + bv;
        if constexpr (EPI == 0) {
          ((float*)outP)[idx] = v;
        } else if constexpr (EPI == 1) {
          ((unsigned short*)outP)[idx] = f2bf(v);
        } else {
          ((float*)outP)[idx] = v + addSrc[idx];
        }
      }
    }
  }
}

// ---------------------------------------------------------------------------
// Tiled transpose + f32 -> bf16 convert:  src [R][C] f32  ->  dst [C][R] bf16
// ---------------------------------------------------------------------------
__launch_bounds__(256)
__global__ void transpose_f32_bf16(const float* __restrict__ src,
                                   unsigned short* __restrict__ dst,
                                   int R, int C, long sB, long dB)
{
  __shared__ float tile[32][33];
  const int z  = blockIdx.z;
  const int r0 = blockIdx.y * 32;
  const int c0 = blockIdx.x * 32;
  const float* s = src + (size_t)z * sB;
  unsigned short* d = dst + (size_t)z * dB;
  const int tx = threadIdx.x;  // 0..31
  const int ty = threadIdx.y;  // 0..7
#pragma unroll
  for (int k = 0; k < 4; ++k)
    tile[ty + 8 * k][tx] = s[(size_t)(r0 + ty + 8 * k) * C + (c0 + tx)];
  __syncthreads();
#pragma unroll
  for (int k = 0; k < 4; ++k)
    d[(size_t)(c0 + ty + 8 * k) * R + (r0 + tx)] = f2bf(tile[tx][ty + 8 * k]);
}

__launch_bounds__(256)
__global__ void convert_f32_bf16(const float* __restrict__ s,
                                 unsigned short* __restrict__ d, int n4)
{
  const int i = blockIdx.x * 256 + threadIdx.x;
  if (i >= n4) return;
  const float4 f = ((const float4*)s)[i];
  ushort4 o;
  o.x = f2bf(f.x); o.y = f2bf(f.y); o.z = f2bf(f.z); o.w = f2bf(f.w);
  ((ushort4*)d)[i] = o;
}

// ---------------------------------------------------------------------------
// In-place row softmax over 1024 bf16 (one block per row)
// ---------------------------------------------------------------------------
__launch_bounds__(256)
__global__ void softmax_row(unsigned short* __restrict__ data, long batchStride)
{
  const int z = blockIdx.y;
  unsigned short* row = data + (size_t)z * batchStride + (size_t)blockIdx.x * 1024;
  const int t = threadIdx.x;
  const int wave = t >> 6, lane = t & 63;
  const ushort4 u = ((const ushort4*)row)[t];
  const float v0 = bf2f(u.x), v1 = bf2f(u.y), v2 = bf2f(u.z), v3 = bf2f(u.w);
  float m = fmaxf(fmaxf(v0, v1), fmaxf(v2, v3));
#pragma unroll
  for (int off = 32; off > 0; off >>= 1) m = fmaxf(m, __shfl_xor(m, off));
  __shared__ float rm[4], rs[4];
  if (lane == 0) rm[wave] = m;
  __syncthreads();
  m = fmaxf(fmaxf(rm[0], rm[1]), fmaxf(rm[2], rm[3]));
  const float e0 = __expf(v0 - m), e1 = __expf(v1 - m);
  const float e2 = __expf(v2 - m), e3 = __expf(v3 - m);
  float s = e0 + e1 + e2 + e3;
#pragma unroll
  for (int off = 32; off > 0; off >>= 1) s += __shfl_xor(s, off);
  if (lane == 0) rs[wave] = s;
  __syncthreads();
  const float inv = 1.f / (rs[0] + rs[1] + rs[2] + rs[3]);
  ushort4 o;
  o.x = f2bf(e0 * inv); o.y = f2bf(e1 * inv);
  o.z = f2bf(e2 * inv); o.w = f2bf(e3 * inv);
  ((ushort4*)row)[t] = o;
}

// ---------------------------------------------------------------------------
// In-place column softmax (over the 1024 rows) of a [1024][1024] bf16 matrix.
// Block: 256 threads = 64 columns x 4 row-stripes. Coalesced both passes.
// ---------------------------------------------------------------------------
__launch_bounds__(256)
__global__ void softmax_col(unsigned short* __restrict__ data, long batchStride,
                            long baseOff)
{
  const int z = blockIdx.y;
  unsigned short* D = data + (size_t)z * batchStride + baseOff;
  const int jl  = threadIdx.x & 63;
  const int j   = blockIdx.x * 64 + jl;
  const int rs0 = threadIdx.x >> 6;
  float m = -3.0e38f, s = 0.f;
  for (int r = rs0; r < 1024; r += 4) {
    const float v = bf2f(D[(size_t)r * 1024 + j]);
    const float nm = fmaxf(m, v);
    s = s * __expf(m - nm) + __expf(v - nm);
    m = nm;
  }
  __shared__ float sm[4][64], ss[4][64], fm[64], fs[64];
  sm[rs0][jl] = m;
  ss[rs0][jl] = s;
  __syncthreads();
  if (threadIdx.x < 64) {
    const float M = fmaxf(fmaxf(sm[0][jl], sm[1][jl]), fmaxf(sm[2][jl], sm[3][jl]));
    const float S = ss[0][jl] * __expf(sm[0][jl] - M) + ss[1][jl] * __expf(sm[1][jl] - M) +
                    ss[2][jl] * __expf(sm[2][jl] - M) + ss[3][jl] * __expf(sm[3][jl] - M);
    fm[jl] = M;
    fs[jl] = 1.f / S;
  }
  __syncthreads();
  const float M = fm[jl], inv = fs[jl];
  for (int r = rs0; r < 1024; r += 4) {
    const size_t idx = (size_t)r * 1024 + j;
    D[idx] = f2bf(__expf(bf2f(D[idx]) - M) * inv);
  }
}

// ---------------------------------------------------------------------------
// B=32, CIN=2048, CO=HW=1024.
// ws layout:
//   [0,128MiB)   : xT bf16 [32][1024][2048]  -> reused as logits [32][2048][1024]
//   [128,192MiB) : YT bf16 [32][1024][1024]
//   [192,196MiB) : wr bf16 [1024][2048]
//   [196,200MiB) : wcd bf16 [2048][1024]
//   [200MiB,+8K) : bcd f32 [2048]
// Y_f32 lives in d_out (GEMM3 epilogue does disjoint read-modify-write).
// ---------------------------------------------------------------------------
extern "C" void kernel_launch(void* const* d_in, const int* in_sizes, int n_in,
                              void* d_out, int out_size, void* d_ws, size_t ws_size,
                              hipStream_t stream)
{
  (void)in_sizes; (void)n_in; (void)out_size; (void)ws_size;
  const float* x  = (const float*)d_in[0];
  const float* wr = (const float*)d_in[1];
  const float* br = (const float*)d_in[2];
  const float* wc = (const float*)d_in[3];
  const float* bc = (const float*)d_in[4];
  const float* wd = (const float*)d_in[5];
  const float* bd = (const float*)d_in[6];

  const size_t MiB = 1024 * 1024;
  char* ws = (char*)d_ws;
  unsigned short* xT   = (unsigned short*)ws;                  // region A
  unsigned short* Lout = (unsigned short*)ws;                  // region A (reuse)
  unsigned short* YT   = (unsigned short*)(ws + 128 * MiB);
  unsigned short* wrB  = (unsigned short*)(ws + 192 * MiB);
  unsigned short* wcdB = (unsigned short*)(ws + 196 * MiB);
  float*          bcd  = (float*)(ws + 200 * MiB);
  float*          Yf   = (float*)d_out;

  // Weights -> bf16 (wc/wd stacked into one [2048][1024] matrix)
  convert_f32_bf16<<<2048, 256, 0, stream>>>(wr, wrB, 524288);
  convert_f32_bf16<<<1024, 256, 0, stream>>>(wc, wcdB, 262144);
  convert_f32_bf16<<<1024, 256, 0, stream>>>(wd, wcdB + 1048576, 262144);
  hipMemcpyAsync(bcd,        bc, 1024 * sizeof(float), hipMemcpyDeviceToDevice, stream);
  hipMemcpyAsync(bcd + 1024, bd, 1024 * sizeof(float), hipMemcpyDeviceToDevice, stream);

  // x [b][2048][1024] f32 -> xT [b][1024][2048] bf16
  transpose_f32_bf16<<<dim3(32, 64, 32), dim3(32, 8), 0, stream>>>(
      x, xT, 2048, 1024, (long)2048 * 1024, (long)1024 * 2048);

  // GEMM1: Y[b][o][n] = wr[o][:] . xT[b][n][:] + br[o]   (f32 into d_out)
  gemm_abt<0><<<dim3(8, 8, 32), 256, 0, stream>>>(
      wrB, 0L, xT, (long)1024 * 2048, br, nullptr, (void*)Yf,
      (long)1024 * 1024, 1024, 2048);

  // Y f32 -> YT bf16 [b][n][c]
  transpose_f32_bf16<<<dim3(32, 32, 32), dim3(32, 8), 0, stream>>>(
      Yf, YT, 1024, 1024, (long)1024 * 1024, (long)1024 * 1024);

  // GEMM2: logits[b][o][n] = wcd[o][:] . YT[b][n][:] + bcd[o]  (bf16, o in [0,2048))
  gemm_abt<1><<<dim3(8, 16, 32), 256, 0, stream>>>(
      wcdB, 0L, YT, (long)1024 * 1024, bcd, nullptr, (void*)Lout,
      (long)2048 * 1024, 1024, 1024);

  // collect half: softmax over n (rows); distribute half: softmax over d (cols)
  softmax_row<<<dim3(1024, 32), 256, 0, stream>>>(Lout, (long)2048 * 1024);
  softmax_col<<<dim3(16, 32), 256, 0, stream>>>(Lout, (long)2048 * 1024, (long)1024 * 1024);

  // GEMM3: out[b][c][d] = Csm[b][c][:] . Dsm[b][d][:] + Y[b][c][d]
  gemm_abt<2><<<dim3(8, 8, 32), 256, 0, stream>>>(
      Lout, (long)2048 * 1024, Lout + (size_t)1024 * 1024, (long)2048 * 1024,
      nullptr, Yf, (void*)d_out, (long)1024 * 1024, 1024, 1024);
}

// Round 2
// 973.701 us; speedup vs baseline: 1.1375x; 1.1375x over previous
//
#include <hip/hip_runtime.h>
#include <stdint.h>

typedef __attribute__((ext_vector_type(8))) short short8;
typedef __attribute__((ext_vector_type(4))) float floatx4;

#define GLOAD_LDS16(gp, lp)                                        \
  __builtin_amdgcn_global_load_lds(                                \
      (const __attribute__((address_space(1))) void*)(gp),         \
      (__attribute__((address_space(3))) void*)(lp), 16, 0, 0)

__device__ __forceinline__ float bf2f(unsigned short u) {
  union { unsigned int i; float f; } x;
  x.i = ((unsigned int)u) << 16;
  return x.f;
}
__device__ __forceinline__ unsigned short f2bf(float f) {
  union { float f; unsigned int i; } x;
  x.f = f;
  unsigned int r = x.i + 0x7FFFu + ((x.i >> 16) & 1u);
  return (unsigned short)(r >> 16);
}

// ---------------------------------------------------------------------------
// Generic A*B^T GEMM, bf16 inputs, f32 accumulate.
//   A  : [M][K] row-major bf16 (+ z*strideA)
//   Bt : [N][K] row-major bf16 (+ z*strideB)
//   out[z*strideOut + row*N + col]
// EPI 0: f32 out = acc + bias[row]
// EPI 1: bf16 out = acc + bias[row]
// EPI 2: f32 out = acc + addSrc[idx]   (addSrc may alias outP; disjoint idx)
// Tile: BM=BN=128, BK=64, 256 threads (4 waves, each 64x64 out).
// 1D grid with bijective XCD swizzle (nwg % 8 == 0 for all our launches):
// each XCD owns nwg/8 consecutive work items -> whole batches -> weight
// panel stays in its private L2.
// ---------------------------------------------------------------------------
template <int EPI>
__launch_bounds__(256, 2)
__global__ void gemm_abt(const unsigned short* __restrict__ A, long strideA,
                         const unsigned short* __restrict__ Bt, long strideB,
                         const float* __restrict__ bias,
                         const float* addSrc, void* outP,
                         long strideOut, int N, int K, int nbx, int nby)
{
  __shared__ short Asm[128 * 64];
  __shared__ short Bsm[128 * 64];

  const int nwg = gridDim.x;
  const int bid = blockIdx.x;
  const int q   = nwg >> 3;
  const int swz = (bid & 7) * q + (bid >> 3);
  const int bx  = swz % nbx;
  const int by  = (swz / nbx) % nby;
  const int z   = swz / (nbx * nby);

  const int tid  = threadIdx.x;
  const int wave = tid >> 6;
  const int lane = tid & 63;
  const int m0 = by * 128;
  const int n0 = bx * 128;

  const unsigned short* Ab = A  + (size_t)z * strideA;
  const unsigned short* Bb = Bt + (size_t)z * strideB;

  // Staging: wave w stages rows [w*32, w*32+32) of each tile, 4 insts x 8 rows.
  // lane -> local row (lane>>3), 16B chunk (lane&7); data chunk = (lane&7)^(row&7).
  const int lr  = lane >> 3;
  const int swzc = (lane & 7) ^ lr;
  const unsigned short* gA = Ab + (size_t)(m0 + wave * 32 + lr) * K + swzc * 8;
  const unsigned short* gB = Bb + (size_t)(n0 + wave * 32 + lr) * K + swzc * 8;
  short* lA = Asm + wave * 32 * 64;
  short* lB = Bsm + wave * 32 * 64;

  floatx4 acc[4][4];
#pragma unroll
  for (int i = 0; i < 4; ++i)
#pragma unroll
    for (int j = 0; j < 4; ++j)
#pragma unroll
      for (int p = 0; p < 4; ++p) acc[i][j][p] = 0.f;

  const int g    = lane >> 4;       // k-group 0..3
  const int ln16 = lane & 15;       // frag row/col
  const int wr   = (wave >> 1) * 64;
  const int wc   = (wave & 1) * 64;
  const int xm   = (lane & 7) * 8;  // xor mask in elements (row&7 == lane&7 for frag rows)
  const int ck0  = (g * 8) ^ xm;    // k-step 0 column offset (swizzled)
  const int ck1  = (32 + g * 8) ^ xm;

  const int nkt = K >> 6;
  for (int kt = 0; kt < nkt; ++kt) {
#pragma unroll
    for (int i = 0; i < 4; ++i) {
      GLOAD_LDS16(gA + (size_t)i * 8 * K, lA + i * 512);
      GLOAD_LDS16(gB + (size_t)i * 8 * K, lB + i * 512);
    }
    __syncthreads();   // compiler emits vmcnt(0) drain before barrier
#pragma unroll
    for (int kk = 0; kk < 2; ++kk) {
      const int ck = kk ? ck1 : ck0;
      short8 a[4], b[4];
#pragma unroll
      for (int m = 0; m < 4; ++m)
        a[m] = *(const short8*)(Asm + (wr + m * 16 + ln16) * 64 + ck);
#pragma unroll
      for (int n = 0; n < 4; ++n)
        b[n] = *(const short8*)(Bsm + (wc + n * 16 + ln16) * 64 + ck);
#pragma unroll
      for (int m = 0; m < 4; ++m)
#pragma unroll
        for (int n = 0; n < 4; ++n)
          acc[m][n] = __builtin_amdgcn_mfma_f32_16x16x32_bf16(a[m], b[n], acc[m][n], 0, 0, 0);
    }
    __syncthreads();
    gA += 64;
    gB += 64;
  }

  // Epilogue. C/D frag: col = lane&15, row = (lane>>4)*4 + q  [m89-verified]
#pragma unroll
  for (int m = 0; m < 4; ++m) {
#pragma unroll
    for (int p = 0; p < 4; ++p) {
      const int row = m0 + wr + m * 16 + g * 4 + p;
      float bv = 0.f;
      if constexpr (EPI != 2) bv = bias[row];
#pragma unroll
      for (int n = 0; n < 4; ++n) {
        const int col = n0 + wc + n * 16 + ln16;
        const size_t idx = (size_t)z * strideOut + (size_t)row * N + col;
        const float v = acc[m][n][p] + bv;
        if constexpr (EPI == 0) {
          ((float*)outP)[idx] = v;
        } else if constexpr (EPI == 1) {
          ((unsigned short*)outP)[idx] = f2bf(v);
        } else {
          ((float*)outP)[idx] = v + addSrc[idx];
        }
      }
    }
  }
}

// ---------------------------------------------------------------------------
// Tiled transpose + f32 -> bf16:  src [R][C] f32 -> dst [C][R] bf16.
// 64x64 tile, 256 threads. float4 global loads; LDS [64][65] (both phases
// measured-free 2-way bank aliasing); short8 global stores.
// ---------------------------------------------------------------------------
__launch_bounds__(256)
__global__ void transpose_f32_bf16(const float* __restrict__ src,
                                   unsigned short* __restrict__ dst,
                                   int R, int C, long sB, long dB)
{
  __shared__ float tile[64][65];
  const int z  = blockIdx.z;
  const int r0 = blockIdx.y * 64;
  const int c0 = blockIdx.x * 64;
  const float* s = src + (size_t)z * sB;
  unsigned short* d = dst + (size_t)z * dB;
  const int t  = threadIdx.x;
  const int tx = t & 15;   // 16 col-chunks of 4
  const int ty = t >> 4;   // 16 row slots
#pragma unroll
  for (int k = 0; k < 4; ++k) {
    const int row = ty + 16 * k;
    const float4 v = *(const float4*)(s + (size_t)(r0 + row) * C + (c0 + 4 * tx));
    tile[row][4 * tx + 0] = v.x;
    tile[row][4 * tx + 1] = v.y;
    tile[row][4 * tx + 2] = v.z;
    tile[row][4 * tx + 3] = v.w;
  }
  __syncthreads();
  const int cc = t >> 3;   // 32 cols per iter
  const int rc = t & 7;    // 8 r-chunks of 8
#pragma unroll
  for (int k = 0; k < 2; ++k) {
    const int c = cc + 32 * k;
    short8 o;
#pragma unroll
    for (int j = 0; j < 8; ++j) o[j] = (short)f2bf(tile[8 * rc + j][c]);
    *(short8*)(d + (size_t)(c0 + c) * R + (r0 + 8 * rc)) = o;
  }
}

__launch_bounds__(256)
__global__ void convert_f32_bf16(const float* __restrict__ s,
                                 unsigned short* __restrict__ d, int n4)
{
  const int i = blockIdx.x * 256 + threadIdx.x;
  if (i >= n4) return;
  const float4 f = ((const float4*)s)[i];
  ushort4 o;
  o.x = f2bf(f.x); o.y = f2bf(f.y); o.z = f2bf(f.z); o.w = f2bf(f.w);
  ((ushort4*)d)[i] = o;
}

// ---------------------------------------------------------------------------
// In-place row softmax over 1024 bf16 (one block per row)
// ---------------------------------------------------------------------------
__launch_bounds__(256)
__global__ void softmax_row(unsigned short* __restrict__ data, long batchStride)
{
  const int z = blockIdx.y;
  unsigned short* row = data + (size_t)z * batchStride + (size_t)blockIdx.x * 1024;
  const int t = threadIdx.x;
  const int wave = t >> 6, lane = t & 63;
  const ushort4 u = ((const ushort4*)row)[t];
  const float v0 = bf2f(u.x), v1 = bf2f(u.y), v2 = bf2f(u.z), v3 = bf2f(u.w);
  float m = fmaxf(fmaxf(v0, v1), fmaxf(v2, v3));
#pragma unroll
  for (int off = 32; off > 0; off >>= 1) m = fmaxf(m, __shfl_xor(m, off));
  __shared__ float rm[4], rs[4];
  if (lane == 0) rm[wave] = m;
  __syncthreads();
  m = fmaxf(fmaxf(rm[0], rm[1]), fmaxf(rm[2], rm[3]));
  const float e0 = __expf(v0 - m), e1 = __expf(v1 - m);
  const float e2 = __expf(v2 - m), e3 = __expf(v3 - m);
  float s = e0 + e1 + e2 + e3;
#pragma unroll
  for (int off = 32; off > 0; off >>= 1) s += __shfl_xor(s, off);
  if (lane == 0) rs[wave] = s;
  __syncthreads();
  const float inv = 1.f / (rs[0] + rs[1] + rs[2] + rs[3]);
  ushort4 o;
  o.x = f2bf(e0 * inv); o.y = f2bf(e1 * inv);
  o.z = f2bf(e2 * inv); o.w = f2bf(e3 * inv);
  ((ushort4*)row)[t] = o;
}

// ---------------------------------------------------------------------------
// In-place column softmax (over 1024 rows) of [1024][1024] bf16.
// Grid (16 chunks of 64 cols, 32 batches), 256 threads.
// Thread = (tx = 8 col-groups of 8, ty = 32 row stripes). short8 loads,
// 3 passes (max / sum / write); passes 2-3 hit L2/L3. No serial exp chain.
// ---------------------------------------------------------------------------
__launch_bounds__(256)
__global__ void softmax_col(unsigned short* __restrict__ data, long batchStride,
                            long baseOff)
{
  __shared__ float red[32][64];
  const int z = blockIdx.y;
  unsigned short* D = data + (size_t)z * batchStride + baseOff + blockIdx.x * 64;
  const int tx = threadIdx.x & 7;
  const int ty = threadIdx.x >> 3;
  const int cb = tx * 8;

  float M[8];
#pragma unroll
  for (int j = 0; j < 8; ++j) M[j] = -3.0e38f;
#pragma unroll 4
  for (int r = ty; r < 1024; r += 32) {
    const short8 v = *(const short8*)(D + (size_t)r * 1024 + cb);
#pragma unroll
    for (int j = 0; j < 8; ++j) M[j] = fmaxf(M[j], bf2f((unsigned short)v[j]));
  }
#pragma unroll
  for (int j = 0; j < 8; ++j) red[ty][cb + j] = M[j];
  for (int h = 16; h >= 1; h >>= 1) {
    __syncthreads();
    if (ty < h) {
#pragma unroll
      for (int j = 0; j < 8; ++j)
        red[ty][cb + j] = fmaxf(red[ty][cb + j], red[ty + h][cb + j]);
    }
  }
  __syncthreads();
#pragma unroll
  for (int j = 0; j < 8; ++j) M[j] = red[0][cb + j];
  __syncthreads();

  float S[8];
#pragma unroll
  for (int j = 0; j < 8; ++j) S[j] = 0.f;
#pragma unroll 4
  for (int r = ty; r < 1024; r += 32) {
    const short8 v = *(const short8*)(D + (size_t)r * 1024 + cb);
#pragma unroll
    for (int j = 0; j < 8; ++j) S[j] += __expf(bf2f((unsigned short)v[j]) - M[j]);
  }
#pragma unroll
  for (int j = 0; j < 8; ++j) red[ty][cb + j] = S[j];
  for (int h = 16; h >= 1; h >>= 1) {
    __syncthreads();
    if (ty < h) {
#pragma unroll
      for (int j = 0; j < 8; ++j)
        red[ty][cb + j] += red[ty + h][cb + j];
    }
  }
  __syncthreads();
  float I[8];
#pragma unroll
  for (int j = 0; j < 8; ++j) I[j] = 1.f / red[0][cb + j];

#pragma unroll 2
  for (int r = ty; r < 1024; r += 32) {
    const size_t off = (size_t)r * 1024 + cb;
    const short8 v = *(const short8*)(D + off);
    short8 o;
#pragma unroll
    for (int j = 0; j < 8; ++j)
      o[j] = (short)f2bf(__expf(bf2f((unsigned short)v[j]) - M[j]) * I[j]);
    *(short8*)(D + off) = o;
  }
}

// ---------------------------------------------------------------------------
// B=32, CIN=2048, CO=HW=1024.
// ws layout:
//   [0,128MiB)   : xT bf16 [32][1024][2048]  -> reused as logits [32][2048][1024]
//   [128,192MiB) : YT bf16 [32][1024][1024]
//   [192,196MiB) : wr bf16 [1024][2048]
//   [196,200MiB) : wcd bf16 [2048][1024]
//   [200MiB,+8K) : bcd f32 [2048]
// Y_f32 lives in d_out (GEMM3 epilogue does disjoint read-modify-write).
// ---------------------------------------------------------------------------
extern "C" void kernel_launch(void* const* d_in, const int* in_sizes, int n_in,
                              void* d_out, int out_size, void* d_ws, size_t ws_size,
                              hipStream_t stream)
{
  (void)in_sizes; (void)n_in; (void)out_size; (void)ws_size;
  const float* x  = (const float*)d_in[0];
  const float* wr = (const float*)d_in[1];
  const float* br = (const float*)d_in[2];
  const float* wc = (const float*)d_in[3];
  const float* bc = (const float*)d_in[4];
  const float* wd = (const float*)d_in[5];
  const float* bd = (const float*)d_in[6];

  const size_t MiB = 1024 * 1024;
  char* ws = (char*)d_ws;
  unsigned short* xT   = (unsigned short*)ws;                  // region A
  unsigned short* Lout = (unsigned short*)ws;                  // region A (reuse)
  unsigned short* YT   = (unsigned short*)(ws + 128 * MiB);
  unsigned short* wrB  = (unsigned short*)(ws + 192 * MiB);
  unsigned short* wcdB = (unsigned short*)(ws + 196 * MiB);
  float*          bcd  = (float*)(ws + 200 * MiB);
  float*          Yf   = (float*)d_out;

  // Weights -> bf16 (wc/wd stacked into one [2048][1024] matrix)
  convert_f32_bf16<<<2048, 256, 0, stream>>>(wr, wrB, 524288);
  convert_f32_bf16<<<1024, 256, 0, stream>>>(wc, wcdB, 262144);
  convert_f32_bf16<<<1024, 256, 0, stream>>>(wd, wcdB + 1048576, 262144);
  hipMemcpyAsync(bcd,        bc, 1024 * sizeof(float), hipMemcpyDeviceToDevice, stream);
  hipMemcpyAsync(bcd + 1024, bd, 1024 * sizeof(float), hipMemcpyDeviceToDevice, stream);

  // x [b][2048][1024] f32 -> xT [b][1024][2048] bf16
  transpose_f32_bf16<<<dim3(16, 32, 32), 256, 0, stream>>>(
      x, xT, 2048, 1024, (long)2048 * 1024, (long)1024 * 2048);

  // GEMM1: Y[b][o][n] = wr[o][:] . xT[b][n][:] + br[o]   (f32 into d_out)
  gemm_abt<0><<<2048, 256, 0, stream>>>(
      wrB, 0L, xT, (long)1024 * 2048, br, nullptr, (void*)Yf,
      (long)1024 * 1024, 1024, 2048, 8, 8);

  // Y f32 -> YT bf16 [b][n][c]
  transpose_f32_bf16<<<dim3(16, 16, 32), 256, 0, stream>>>(
      Yf, YT, 1024, 1024, (long)1024 * 1024, (long)1024 * 1024);

  // GEMM2: logits[b][o][n] = wcd[o][:] . YT[b][n][:] + bcd[o]  (bf16, o in [0,2048))
  gemm_abt<1><<<4096, 256, 0, stream>>>(
      wcdB, 0L, YT, (long)1024 * 1024, bcd, nullptr, (void*)Lout,
      (long)2048 * 1024, 1024, 1024, 8, 16);

  // collect half: softmax over n (rows); distribute half: softmax over d (cols)
  softmax_row<<<dim3(1024, 32), 256, 0, stream>>>(Lout, (long)2048 * 1024);
  softmax_col<<<dim3(16, 32), 256, 0, stream>>>(Lout, (long)2048 * 1024, (long)1024 * 1024);

  // GEMM3: out[b][c][d] = Csm[b][c][:] . Dsm[b][d][:] + Y[b][c][d]
  gemm_abt<2><<<2048, 256, 0, stream>>>(
      Lout, (long)2048 * 1024, Lout + (size_t)1024 * 1024, (long)2048 * 1024,
      nullptr, Yf, (void*)d_out, (long)1024 * 1024, 1024, 1024, 8, 8);
}